// Round 1
// baseline (232.770 us; speedup 1.0000x reference)
//
#include <hip/hip_runtime.h>
#include <stdint.h>

// Problem constants (B=64, S=512 -> 32768 tokens)
#define N_TOK 32768
#define DIN   512
#define DFF   1024
#define MPAD  33792   // 32768 + 8*128 worst-case bucket padding

// fp8 rotation convention: within each 128B K-window, row data is rotated by
// (row mod 16)*8 bytes: phys = (k & ~127) + (((k&127) + (row&15)*8) & 127).
// Same permutation on A-rows and B-rows => dot product unchanged. Staging is
// then a linear aligned copy; fragment reads cover all 32 banks (conflict-free).
__device__ __forceinline__ int rotk(int k, int row) {
    return (k & ~127) + (((k & 127) + ((row & 15) << 3)) & 127);
}

typedef __attribute__((ext_vector_type(8))) short bf16x8;
typedef __attribute__((ext_vector_type(4))) float f32x4;

__device__ __forceinline__ unsigned short f2bf(float f) {
    union { float f; unsigned int u; } v; v.f = f;
    unsigned int u = v.u;
    return (unsigned short)((u + 0x7FFFu + ((u >> 16) & 1u)) >> 16);
}
__device__ __forceinline__ float bf2f(unsigned int bits) {
    union { unsigned int u; float f; } v; v.u = bits << 16; return v.f;
}
// pack 4 floats -> 4 OCP e4m3 bytes (hw cvt, saturating)
__device__ __forceinline__ unsigned int pk4_fp8(float a, float b, float c, float d) {
    int v = __builtin_amdgcn_cvt_pk_fp8_f32(a, b, 0, false);
    v = __builtin_amdgcn_cvt_pk_fp8_f32(c, d, v, true);
    return (unsigned int)v;
}
__device__ __forceinline__ unsigned char f2fp8(float a) {
    return (unsigned char)(__builtin_amdgcn_cvt_pk_fp8_f32(a, a, 0, false) & 0xFF);
}

// async 16B global -> LDS (wave-uniform LDS base + lane*16 pattern)
__device__ __forceinline__ void async16(const void* g, void* l) {
    __builtin_amdgcn_global_load_lds(
        (const __attribute__((address_space(1))) void*)g,
        (__attribute__((address_space(3))) void*)l, 16, 0, 0);
}

// ---------------- merged prep: tokens + weights + perm-pad in ONE launch -------
// blocks [0,16384): x -> bf16 Xb + fp8 Xb8 (rotated); blocks 0..63 also
//   histogram their 512 tokens into blockhist[blk][8] (LDS, no global atomics).
// blocks [16384, 26624): weight transpose+cast, z = (b-16384)/1024:
//   z=0: W_pre -> Wp8 [1024][512] fp8 x64 rotated
//   z=1..8: W_types[z-1] -> Wt8 [512][1024] fp8 x64 rotated
//   z=9: W_c1 -> WcT bf16 [512][512] plain
// blocks [26624, 26756): perm[i] = -1 (MPAD entries)
__global__ void prep_kernel(const float* __restrict__ x,
                            unsigned short* __restrict__ Xb,
                            unsigned char* __restrict__ Xb8,
                            const int* __restrict__ types,
                            int* __restrict__ blockhist,
                            const float* __restrict__ Wp,
                            const float* __restrict__ Wt,
                            const float* __restrict__ Wc,
                            unsigned char* __restrict__ Wp8,
                            unsigned char* __restrict__ Wt8,
                            unsigned short* __restrict__ WcT,
                            int* __restrict__ perm) {
    __shared__ float tile[32][33];
    __shared__ int lc[8];
    const int b = blockIdx.x, tid = threadIdx.x;
    if (b < 16384) {
        const int i = b * 1024 + tid * 4;
        float4 v = *(const float4*)(x + i);
        ushort4 o;
        o.x = f2bf(v.x); o.y = f2bf(v.y); o.z = f2bf(v.z); o.w = f2bf(v.w);
        *(ushort4*)(Xb + i) = o;
        const int row = i >> 9;             // DIN=512
        const int k   = i & 511;
        *(unsigned int*)(Xb8 + (size_t)row * DIN + rotk(k, row)) = pk4_fp8(v.x, v.y, v.z, v.w);
        if (b < 64) {
            if (tid < 8) lc[tid] = 0;
            __syncthreads();
            atomicAdd(&lc[types[b * 512 + tid]], 1);
            atomicAdd(&lc[types[b * 512 + 256 + tid]], 1);
            __syncthreads();
            if (tid < 8) blockhist[b * 8 + tid] = lc[tid];
        }
    } else if (b < 26624) {
        const int r = b - 16384;
        const int z = r >> 10;
        const int bx = r & 31, by = (r >> 5) & 31;
        const int tx = tid & 31, ty = tid >> 5;
        const float* s; int K, N;
        if (z == 0)      { s = Wp;                          K = 512;  N = 1024; }
        else if (z <= 8) { s = Wt + (size_t)(z-1)*DIN*DFF;  K = 1024; N = 512; }
        else             { s = Wc;                          K = 512;  N = 512; }
        const int n0 = bx * 32, k0 = by * 32;
        if (n0 >= N || k0 >= K) return;
        for (int i = ty; i < 32; i += 8)
            tile[i][tx] = s[(size_t)(k0 + i) * N + n0 + tx];
        __syncthreads();
        if (z == 0) {
            for (int i = ty; i < 32; i += 8) {
                int n = n0 + i;
                Wp8[(size_t)n * K + rotk(k0 + tx, n)] = f2fp8(tile[tx][i] * 64.f);
            }
        } else if (z <= 8) {
            unsigned char* d = Wt8 + (size_t)(z-1)*DIN*DFF;
            for (int i = ty; i < 32; i += 8) {
                int n = n0 + i;
                d[(size_t)n * K + rotk(k0 + tx, n)] = f2fp8(tile[tx][i] * 64.f);
            }
        } else {
            for (int i = ty; i < 32; i += 8)
                WcT[(size_t)(n0 + i) * K + k0 + tx] = f2bf(tile[tx][i]);
        }
    } else {
        perm[(b - 26624) * 256 + tid] = -1;
    }
}

// ---- atomic-free scatter: 64 blocks x 512 threads, deterministic placement ----
// totals + padded prefix derived from blockhist alone; block 0 publishes po[9]
// for GEMM2. Intra-block rank via LDS atomics only.
__global__ void scatter_kernel(const int* __restrict__ types,
                               const int* __restrict__ blockhist,
                               int* __restrict__ perm,
                               int* __restrict__ invperm,
                               float* __restrict__ outz,
                               int* __restrict__ po_out) {
    __shared__ int tots[8], base[8], fill[8];
    const int blk = blockIdx.x;            // 64
    const int tid = threadIdx.x;           // 512
    const int i = blk * 512 + tid;
    outz[i] = 0.f;
    int pre = 0;
    if (tid < 8) {
        int total = 0;
        for (int j = 0; j < 64; j++) {
            int v = blockhist[j * 8 + tid];
            if (j < blk) pre += v;
            total += v;
        }
        tots[tid] = total;
    }
    __syncthreads();
    if (tid < 8) {
        int off = 0, pob = 0;
        #pragma unroll
        for (int t2 = 0; t2 < 8; t2++) {
            if (t2 == tid) pob = off;
            off += ((tots[t2] + 127) >> 7) << 7;
        }
        base[tid] = pob + pre;
        fill[tid] = 0;
        if (blk == 0) {
            po_out[tid] = pob;
            if (tid == 0) po_out[8] = off;
        }
    }
    __syncthreads();
    const int t = types[i];
    const int r = atomicAdd(&fill[t], 1);  // LDS atomic: intra-block rank
    const int p = base[t] + r;
    perm[p] = i;
    invperm[i] = p;
}

// ---------- GEMM1 (fp8): 256x256 tile, BK=128, 8 waves, phased schedule --------
// T3+T4+T5 port of the m97-style kernel: double-buffered LDS (2 slots of one
// K-tile each), 8 phases per K-tile: {8x ds_read_b64 frags | 2x global_load_lds
// prefetch of K-tile t+1 into the OTHER slot -> s_barrier -> setprio(1) ->
// 16 MFMA -> setprio(0) -> s_barrier}. Prefetch front-loaded (phases 0-3) so
// the single vmcnt(0) at phase 7 only waits on loads issued >=4 phases ago
// (never drains a fresh load -- the T4 mechanism). Raw s_barrier, NOT
// __syncthreads(), so the compiler does not re-insert vmcnt(0) at every phase.
// Fragment rotation math + swapped MFMA (D[n][tok]) + scatter epilogue are
// verbatim from the proven kernel => bit-identical accumulation order.
// Grid: 512 blocks = exactly 2 rounds at 1 block/CU (132KB LDS).
// XCD-bijective swizzle (512%8==0): XCD k owns 16 consecutive M-tiles x all
// 4 N-tiles -> 2MB A-panel stays L2-resident across its 4 reuses.
__global__ __launch_bounds__(512, 2)
void gemm1_fp8_8ph(const unsigned char* __restrict__ A,
                   const unsigned char* __restrict__ B,
                   unsigned char* __restrict__ C8,
                   const int* __restrict__ invperm) {
    __shared__ unsigned char As[2][256 * 128];
    __shared__ unsigned char Bs[2][256 * 128];
    __shared__ int ptile[256];

    const int tid  = threadIdx.x;
    const int wave = tid >> 6;
    const int lane = tid & 63;
    const int quad = lane >> 4;
    const int tl   = lane & 15;

    const int lin  = blockIdx.x;                 // 0..511
    const int sid  = (lin & 7) * 64 + (lin >> 3); // bijective XCD swizzle
    const int m0   = (sid >> 2) * 256;           // token tile
    const int n0   = (sid & 3) * 256;            // ff tile

    const int wm = (wave & 1) * 128;             // wave: 128 rows x 64 cols
    const int wn = (wave >> 1) * 64;

    if (tid < 256) ptile[tid] = invperm[m0 + tid];

    f32x4 acc[8][4];
    #pragma unroll
    for (int i = 0; i < 8; i++)
        #pragma unroll
        for (int j = 0; j < 4; j++)
            acc[i][j] = (f32x4){0.f, 0.f, 0.f, 0.f};

    // prologue: stage K-tile 0 into slot 0 (8 chunks/thread: 4 A + 4 B)
    #pragma unroll
    for (int ci = 0; ci < 8; ++ci) {
        const int c = ci * 512 + tid;
        if (ci < 4) {
            const int row = c >> 3, j = c & 7;
            async16(A + (size_t)(m0 + row) * 512 + j * 16, &As[0][c * 16]);
        } else {
            const int c2 = c - 2048;
            const int row = c2 >> 3, j = c2 & 7;
            async16(B + (size_t)(n0 + row) * 512 + j * 16, &Bs[0][c2 * 16]);
        }
    }
    asm volatile("s_waitcnt vmcnt(0)" ::: "memory");
    __builtin_amdgcn_s_barrier();
    asm volatile("" ::: "memory");

    for (int t = 0; t < 4; ++t) {                 // K = 512, BK = 128
        const unsigned char* Asl = As[t & 1];
        const unsigned char* Bsl = Bs[t & 1];
        unsigned char* Asn = As[(t + 1) & 1];
        unsigned char* Bsn = Bs[(t + 1) & 1];
        const int k0n = (t + 1) * 128;
        const bool st = (t < 3);
        #pragma unroll
        for (int ph = 0; ph < 8; ++ph) {          // ph = ks*2 + mh
            const int ks = ph >> 1, mh = ph & 1;
            const int o = (ks * 32 + quad * 8 + tl * 8) & 127;  // rotated frag offset
            long af[4], bfr[4];
            #pragma unroll
            for (int mt = 0; mt < 4; ++mt)
                af[mt] = *(const long*)(Asl + (wm + mh * 64 + mt * 16 + tl) * 128 + o);
            #pragma unroll
            for (int nt = 0; nt < 4; ++nt)
                bfr[nt] = *(const long*)(Bsl + (wn + nt * 16 + tl) * 128 + o);
            if (st && ph < 4) {
                // prefetch K-tile t+1 into the OTHER slot: 2 chunks/phase
                #pragma unroll
                for (int u = 0; u < 2; ++u) {
                    const int cidx = ph * 2 + u;      // 0..7 (compile-time)
                    const int c = cidx * 512 + tid;
                    if (cidx < 4) {
                        const int row = c >> 3, j = c & 7;
                        async16(A + (size_t)(m0 + row) * 512 + k0n + j * 16, Asn + c * 16);
                    } else {
                        const int c2 = c - 2048;
                        const int row = c2 >> 3, j = c2 & 7;
                        async16(B + (size_t)(n0 + row) * 512 + k0n + j * 16, Bsn + c2 * 16);
                    }
                }
            }
            __builtin_amdgcn_s_barrier();
            asm volatile("" ::: "memory");
            __builtin_amdgcn_s_setprio(1);
            #pragma unroll
            for (int mt = 0; mt < 4; ++mt)
                #pragma unroll
                for (int nt = 0; nt < 4; ++nt)
                    acc[mh * 4 + mt][nt] = __builtin_amdgcn_mfma_f32_16x16x32_fp8_fp8(
                        bfr[nt], af[mt], acc[mh * 4 + mt][nt], 0, 0, 0);  // swapped: D[n][tok]
            __builtin_amdgcn_s_setprio(0);
            if (ph == 7) asm volatile("s_waitcnt vmcnt(0)" ::: "memory");
            __builtin_amdgcn_s_barrier();
            asm volatile("" ::: "memory");
        }
    }

    // epilogue: lane holds 4 consecutive n (regs) for token tl; scatter via invperm
    #pragma unroll
    for (int mh = 0; mh < 2; ++mh)
        #pragma unroll
        for (int mt = 0; mt < 4; ++mt) {
            const int p = ptile[wm + mh * 64 + mt * 16 + tl];   // bucket position
            const size_t rowbase = (size_t)p * DFF;
            const int prot = (p & 15) << 3;
            #pragma unroll
            for (int nt = 0; nt < 4; ++nt) {
                const int off = wn + nt * 16 + quad * 4;        // 0..255 in n-tile
                unsigned int pk = pk4_fp8(fmaxf(acc[mh * 4 + mt][nt][0], 0.f) * 0.125f,
                                          fmaxf(acc[mh * 4 + mt][nt][1], 0.f) * 0.125f,
                                          fmaxf(acc[mh * 4 + mt][nt][2], 0.f) * 0.125f,
                                          fmaxf(acc[mh * 4 + mt][nt][3], 0.f) * 0.125f);
                const int phys = (off & ~127) + (((off & 127) + prot) & 127);
                *(unsigned int*)(C8 + rowbase + n0 + phys) = pk;
            }
        }
}

// ---------- fp8 GEMM (r9 proven): 128x128 tile, BK=128, 4 waves, 16x16x32 fp8 --
// Kept for GEMM2 (MODE 1): its N=512 grid (264 blocks of 256^2) cannot fill the
// 1-block/CU big-tile schedule, so it stays on the 4-block/CU structure.
// MODE 1 (GEMM2): A=Xff8 bucket-order (contiguous); B per bucket via po[];
//                 epilogue via perm: Xb[tok] = bf16(Xb[tok]+relu(acc)/512)
template <int MODE>
__global__ __launch_bounds__(256, 4)
void gemm_fp8_kernel(const unsigned char* __restrict__ A,
                     const unsigned char* __restrict__ B,
                     void* __restrict__ Cout,
                     const unsigned short* __restrict__ xres,
                     const int* __restrict__ pmap,   // MODE0: invperm, MODE1: perm
                     const int* __restrict__ po,     // MODE1 only: padded offsets[9]
                     int K, int ldA) {
    __shared__ unsigned char As[128 * 128];
    __shared__ unsigned char Bs[128 * 128];
    __shared__ int ptile[128];

    const int tid  = threadIdx.x;
    const int wave = tid >> 6;
    const int lane = tid & 63;
    const int quad = lane >> 4;
    const int tl   = lane & 15;
    const int m0 = blockIdx.y * 128;
    const int n0 = blockIdx.x * 128;
    const int wm = (wave & 1) * 64;
    const int wn = (wave >> 1) * 64;

    const unsigned char* Bp = B;
    if constexpr (MODE == 1) {
        if (m0 >= po[8]) return;                  // fully-padded tail block
        int bsel = 0;
        #pragma unroll
        for (int i = 1; i < 8; i++) bsel += (m0 >= po[i]) ? 1 : 0;
        Bp = B + (size_t)bsel * (DIN * DFF);
    }
    if (tid < 128) ptile[tid] = pmap[m0 + tid];

    f32x4 acc[4][4];
    #pragma unroll
    for (int i = 0; i < 4; i++)
        #pragma unroll
        for (int j = 0; j < 4; j++)
            acc[i][j] = (f32x4){0.f, 0.f, 0.f, 0.f};

    for (int k0 = 0; k0 < K; k0 += 128) {
        __syncthreads();
        // A tile [128][128]: 1024 x 16B chunks, 4/thread, LINEAR copy
        #pragma unroll
        for (int i = 0; i < 4; i++) {
            const int c   = (i * 4 + wave) * 64 + lane;
            const int row = c >> 3;
            const int j   = c & 7;
            async16(A + (size_t)(m0 + row) * ldA + k0 + j * 16, (char*)As + (size_t)c * 16);
        }
        // B tile [128][128], linear
        #pragma unroll
        for (int i = 0; i < 4; i++) {
            const int c   = (i * 4 + wave) * 64 + lane;
            const int row = c >> 3;
            const int j   = c & 7;
            async16(Bp + (size_t)(n0 + row) * K + k0 + j * 16, (char*)Bs + (size_t)c * 16);
        }
        __syncthreads();

        #pragma unroll
        for (int ks = 0; ks < 4; ks++) {
            long af[4], bfr[4];
            const int o = (ks * 32 + quad * 8 + tl * 8) & 127;  // rotated frag offset
            #pragma unroll
            for (int t = 0; t < 4; t++)
                af[t] = *(const long*)(As + (wm + t * 16 + tl) * 128 + o);
            #pragma unroll
            for (int t = 0; t < 4; t++)
                bfr[t] = *(const long*)(Bs + (wn + t * 16 + tl) * 128 + o);
            #pragma unroll
            for (int mt = 0; mt < 4; mt++)
                #pragma unroll
                for (int nt = 0; nt < 4; nt++)
                    acc[mt][nt] = __builtin_amdgcn_mfma_f32_16x16x32_fp8_fp8(
                        bfr[nt], af[mt], acc[mt][nt], 0, 0, 0);  // swapped: D[n][tok]
        }
    }

    // epilogue: lane holds 4 consecutive n (regs) for token tl
    if constexpr (MODE == 0) {
        unsigned char* C8 = (unsigned char*)Cout;
        #pragma unroll
        for (int mt = 0; mt < 4; mt++) {
            const int p = ptile[wm + mt * 16 + tl];            // bucket position
            const size_t rowbase = (size_t)p * DFF;
            const int prot = (p & 15) << 3;
            #pragma unroll
            for (int nt = 0; nt < 4; nt++) {
                const int off = wn + nt * 16 + quad * 4;       // in-window offset
                unsigned int pk = pk4_fp8(fmaxf(acc[mt][nt][0], 0.f) * 0.125f,
                                          fmaxf(acc[mt][nt][1], 0.f) * 0.125f,
                                          fmaxf(acc[mt][nt][2], 0.f) * 0.125f,
                                          fmaxf(acc[mt][nt][3], 0.f) * 0.125f);
                const int phys = (off & ~127) + (((off & 127) + prot) & 127);
                *(unsigned int*)(C8 + rowbase + n0 + phys) = pk;
            }
        }
    } else {
        unsigned short* Cb = (unsigned short*)Cout;
        #pragma unroll
        for (int mt = 0; mt < 4; mt++) {
            int tok = ptile[wm + mt * 16 + tl];
            if (tok < 0) continue;
            const size_t rowbase = (size_t)tok * DIN;
            #pragma unroll
            for (int nt = 0; nt < 4; nt++) {
                const int ncol = n0 + wn + nt * 16 + quad * 4;
                ushort4 rv = *(const ushort4*)(xres + rowbase + ncol);
                ushort4 o;
                o.x = f2bf(bf2f(rv.x) + fmaxf(acc[mt][nt][0], 0.f) * 0.001953125f);
                o.y = f2bf(bf2f(rv.y) + fmaxf(acc[mt][nt][1], 0.f) * 0.001953125f);
                o.z = f2bf(bf2f(rv.z) + fmaxf(acc[mt][nt][2], 0.f) * 0.001953125f);
                o.w = f2bf(bf2f(rv.w) + fmaxf(acc[mt][nt][3], 0.f) * 0.001953125f);
                *(ushort4*)(Cb + rowbase + ncol) = o;
            }
        }
    }
}

// ------- bf16 GEMM3 + head (kept full precision): 128x256 tile, 512 thr --------
// out[tok] += relu(Xb @ W_c1) . w2   (atomicAdd partials per n-block)
__global__ __launch_bounds__(512, 4)
void gemm3_kernel(const unsigned short* __restrict__ A,
                  const unsigned short* __restrict__ B,
                  const float* __restrict__ w2,
                  float* __restrict__ outp,
                  int K, int ldA) {
    __shared__ unsigned short As[128 * 64];
    __shared__ unsigned short Bs[256 * 64];

    const int tid  = threadIdx.x;
    const int wave = tid >> 6;
    const int lane = tid & 63;
    const int quad = lane >> 4;
    const int tl   = lane & 15;
    const int m0 = blockIdx.y * 128;
    const int n0 = blockIdx.x * 256;
    const int wm = (wave & 1) * 64;
    const int wn = (wave >> 1) * 64;

    f32x4 acc[4][4];
    #pragma unroll
    for (int i = 0; i < 4; i++)
        #pragma unroll
        for (int j = 0; j < 4; j++)
            acc[i][j] = (f32x4){0.f, 0.f, 0.f, 0.f};

    for (int k0 = 0; k0 < K; k0 += 64) {
        __syncthreads();
        #pragma unroll
        for (int i = 0; i < 2; i++) {
            const int c   = (i * 8 + wave) * 64 + lane;
            const int row = c >> 3;
            const int gj  = (c & 7) ^ (row & 7);
            async16(A + (size_t)(m0 + row) * ldA + k0 + gj * 8, (char*)As + (size_t)c * 16);
        }
        #pragma unroll
        for (int i = 0; i < 4; i++) {
            const int c   = (i * 8 + wave) * 64 + lane;
            const int row = c >> 3;
            const int gj  = (c & 7) ^ (row & 7);
            async16(B + (size_t)(n0 + row) * K + k0 + gj * 8, (char*)Bs + (size_t)c * 16);
        }
        __syncthreads();

        #pragma unroll
        for (int ks = 0; ks < 2; ks++) {
            bf16x8 af[4], bfr[4];
            const int jc = ks * 4 + quad;
            #pragma unroll
            for (int t = 0; t < 4; t++) {
                const int r = wm + t * 16 + tl;
                af[t] = *(const bf16x8*)(As + (r * 8 + (jc ^ (r & 7))) * 8);
            }
            #pragma unroll
            for (int t = 0; t < 4; t++) {
                const int r = wn + t * 16 + tl;
                bfr[t] = *(const bf16x8*)(Bs + (r * 8 + (jc ^ (r & 7))) * 8);
            }
            #pragma unroll
            for (int mt = 0; mt < 4; mt++)
                #pragma unroll
                for (int nt = 0; nt < 4; nt++)
                    acc[mt][nt] = __builtin_amdgcn_mfma_f32_16x16x32_bf16(
                        bfr[nt], af[mt], acc[mt][nt], 0, 0, 0);
        }
    }

    float4 w2v[4];
    #pragma unroll
    for (int nt = 0; nt < 4; nt++)
        w2v[nt] = *(const float4*)(w2 + n0 + wn + nt * 16 + quad * 4);
    #pragma unroll
    for (int mt = 0; mt < 4; mt++) {
        float s = 0.f;
        #pragma unroll
        for (int nt = 0; nt < 4; nt++) {
            s += fmaxf(acc[mt][nt][0], 0.f) * w2v[nt].x;
            s += fmaxf(acc[mt][nt][1], 0.f) * w2v[nt].y;
            s += fmaxf(acc[mt][nt][2], 0.f) * w2v[nt].z;
            s += fmaxf(acc[mt][nt][3], 0.f) * w2v[nt].w;
        }
        s += __shfl_down(s, 32);
        s += __shfl_down(s, 16);
        if (lane < 16) atomicAdd(&outp[m0 + wm + mt * 16 + lane], s);
    }
}

extern "C" void kernel_launch(void* const* d_in, const int* in_sizes, int n_in,
                              void* d_out, int out_size, void* d_ws, size_t ws_size,
                              hipStream_t stream) {
    const float* x      = (const float*)d_in[0];
    const int*   types  = (const int*)d_in[1];
    const float* W_pre  = (const float*)d_in[2];
    const float* W_types= (const float*)d_in[3];
    const float* W_c1   = (const float*)d_in[4];
    const float* W_c2   = (const float*)d_in[5];
    float* out = (float*)d_out;

    // workspace layout (~91 MB):
    char* ws = (char*)d_ws;
    unsigned short* Xb  = (unsigned short*)(ws);                    // bf16 [32768][512], becomes X_res
    unsigned char*  Xff8= (unsigned char*)(ws + 33554432ull);       // fp8 [MPAD][1024] = 8*x_, bucket order, k-rotated
    unsigned char*  Xb8 = (unsigned char*)(ws + 68157440ull);       // fp8 [32768][512] = x, k-rotated
    unsigned char*  Wp8 = (unsigned char*)(ws + 84934656ull);       // fp8 [1024][512] (x64, rotated)
    unsigned char*  Wt8 = (unsigned char*)(ws + 85458944ull);       // fp8 [8][512][1024] (x64, rotated)
    unsigned short* WcT = (unsigned short*)(ws + 89653248ull);      // bf16 [512][512]
    int* perm           = (int*)(ws + 90177536ull);                  // MPAD ints
    int* invperm        = (int*)(ws + 90312704ull);                  // N_TOK ints
    int* po             = (int*)(ws + 90443776ull);                  // 9 ints (padded offsets)
    int* blockhist      = po + 16;                                   // 64*8 ints

    // 1) merged prep: tokens [0,16384), weights [16384,26624), perm-pad [26624,26756)
    prep_kernel<<<26756, 256, 0, stream>>>(x, Xb, Xb8, types, blockhist,
                                           W_pre, W_types, W_c1, Wp8, Wt8, WcT, perm);
    // 2) deterministic scatter + po publish + out zero
    scatter_kernel<<<64, 512, 0, stream>>>(types, blockhist, perm, invperm, out, po);
    // 3) GEMM1 (fp8, 8-phase 256^2): Xff8[invperm[tok]] = fp8(8 * relu(x @ W_pre))
    gemm1_fp8_8ph<<<512, 512, 0, stream>>>(Xb8, Wp8, Xff8, invperm);
    // 4) GEMM2 (fp8, routed): Xb = bf16(Xb + relu(Xff8 @ Wt8[bucket]) / 512)
    gemm_fp8_kernel<1><<<dim3(DIN / 128, MPAD / 128), 256, 0, stream>>>(
        Xff8, Wt8, Xb, Xb, perm, po, 1024, 1024);
    // 5) GEMM3 + head (bf16): out = relu(Xb @ W_c1) @ W_c2
    gemm3_kernel<<<dim3(DIN / 256, N_TOK / 128), 512, 0, stream>>>(
        Xb, WcT, W_c2, out, 512, 512);
}

// Round 2
// 232.667 us; speedup vs baseline: 1.0004x; 1.0004x over previous
//
#include <hip/hip_runtime.h>
#include <stdint.h>

// Problem constants (B=64, S=512 -> 32768 tokens)
#define N_TOK 32768
#define DIN   512
#define DFF   1024
#define MPAD  33792   // 32768 + 8*128 worst-case bucket padding

// fp8 rotation convention: within each 128B K-window, row data is rotated by
// (row mod 16)*8 bytes: phys = (k & ~127) + (((k&127) + (row&15)*8) & 127).
// Same permutation on A-rows and B-rows => dot product unchanged. Staging is
// then a linear aligned copy; fragment reads cover all 32 banks (conflict-free).
__device__ __forceinline__ int rotk(int k, int row) {
    return (k & ~127) + (((k & 127) + ((row & 15) << 3)) & 127);
}

typedef __attribute__((ext_vector_type(8))) short bf16x8;
typedef __attribute__((ext_vector_type(4))) float f32x4;

__device__ __forceinline__ unsigned short f2bf(float f) {
    union { float f; unsigned int u; } v; v.f = f;
    unsigned int u = v.u;
    return (unsigned short)((u + 0x7FFFu + ((u >> 16) & 1u)) >> 16);
}
__device__ __forceinline__ float bf2f(unsigned int bits) {
    union { unsigned int u; float f; } v; v.u = bits << 16; return v.f;
}
// pack 4 floats -> 4 OCP e4m3 bytes (hw cvt, saturating)
__device__ __forceinline__ unsigned int pk4_fp8(float a, float b, float c, float d) {
    int v = __builtin_amdgcn_cvt_pk_fp8_f32(a, b, 0, false);
    v = __builtin_amdgcn_cvt_pk_fp8_f32(c, d, v, true);
    return (unsigned int)v;
}
__device__ __forceinline__ unsigned char f2fp8(float a) {
    return (unsigned char)(__builtin_amdgcn_cvt_pk_fp8_f32(a, a, 0, false) & 0xFF);
}

// async 16B global -> LDS (wave-uniform LDS base + lane*16 pattern)
__device__ __forceinline__ void async16(const void* g, void* l) {
    __builtin_amdgcn_global_load_lds(
        (const __attribute__((address_space(1))) void*)g,
        (__attribute__((address_space(3))) void*)l, 16, 0, 0);
}

// ---------------- merged prep: tokens + weights + perm-pad in ONE launch -------
// blocks [0,16384): x -> bf16 Xb + fp8 Xb8 (rotated); blocks 0..63 also
//   histogram their 512 tokens into blockhist[blk][8] (LDS, no global atomics).
// blocks [16384, 26624): weight transpose+cast, z = (b-16384)/1024:
//   z=0: W_pre -> Wp8 [1024][512] fp8 x64 rotated
//   z=1..8: W_types[z-1] -> Wt8 [512][1024] fp8 x64 rotated
//   z=9: W_c1 -> WcT bf16 [512][512] plain
// fp8 weight stores are 4B-packed (pk4 of 4 consecutive k; rotation is a
// multiple of 8B and the 4-run is 4-aligned => never wraps the 128B window,
// per-byte values identical to the old 1B path).
// blocks [26624, 26756): perm[i] = -1 (MPAD entries)
__global__ void prep_kernel(const float* __restrict__ x,
                            unsigned short* __restrict__ Xb,
                            unsigned char* __restrict__ Xb8,
                            const int* __restrict__ types,
                            int* __restrict__ blockhist,
                            const float* __restrict__ Wp,
                            const float* __restrict__ Wt,
                            const float* __restrict__ Wc,
                            unsigned char* __restrict__ Wp8,
                            unsigned char* __restrict__ Wt8,
                            unsigned short* __restrict__ WcT,
                            int* __restrict__ perm) {
    __shared__ float tile[32][33];
    __shared__ int lc[8];
    const int b = blockIdx.x, tid = threadIdx.x;
    if (b < 16384) {
        const int i = b * 1024 + tid * 4;
        float4 v = *(const float4*)(x + i);
        ushort4 o;
        o.x = f2bf(v.x); o.y = f2bf(v.y); o.z = f2bf(v.z); o.w = f2bf(v.w);
        *(ushort4*)(Xb + i) = o;
        const int row = i >> 9;             // DIN=512
        const int k   = i & 511;
        *(unsigned int*)(Xb8 + (size_t)row * DIN + rotk(k, row)) = pk4_fp8(v.x, v.y, v.z, v.w);
        if (b < 64) {
            if (tid < 8) lc[tid] = 0;
            __syncthreads();
            atomicAdd(&lc[types[b * 512 + tid]], 1);
            atomicAdd(&lc[types[b * 512 + 256 + tid]], 1);
            __syncthreads();
            if (tid < 8) blockhist[b * 8 + tid] = lc[tid];
        }
    } else if (b < 26624) {
        const int r = b - 16384;
        const int z = r >> 10;
        const int bx = r & 31, by = (r >> 5) & 31;
        const int tx = tid & 31, ty = tid >> 5;
        const float* s; int K, N;
        if (z == 0)      { s = Wp;                          K = 512;  N = 1024; }
        else if (z <= 8) { s = Wt + (size_t)(z-1)*DIN*DFF;  K = 1024; N = 512; }
        else             { s = Wc;                          K = 512;  N = 512; }
        const int n0 = bx * 32, k0 = by * 32;
        if (n0 >= N || k0 >= K) return;
        for (int i = ty; i < 32; i += 8)
            tile[i][tx] = s[(size_t)(k0 + i) * N + n0 + tx];
        __syncthreads();
        if (z <= 8) {
            // 4B-packed fp8 store: thread owns (1 n, 4 consecutive k)
            unsigned char* d = (z == 0) ? Wp8 : (Wt8 + (size_t)(z-1)*DIN*DFF);
            const int nl = tid >> 3;            // 0..31
            const int k4 = (tid & 7) << 2;      // 0,4,..,28
            const int n  = n0 + nl;
            const int kk = k0 + k4;
            unsigned int pk = pk4_fp8(tile[k4 + 0][nl] * 64.f, tile[k4 + 1][nl] * 64.f,
                                      tile[k4 + 2][nl] * 64.f, tile[k4 + 3][nl] * 64.f);
            *(unsigned int*)(d + (size_t)n * K + rotk(kk, n)) = pk;
        } else {
            for (int i = ty; i < 32; i += 8)
                WcT[(size_t)(n0 + i) * K + k0 + tx] = f2bf(tile[tx][i]);
        }
    } else {
        perm[(b - 26624) * 256 + tid] = -1;
    }
}

// ---- atomic-free scatter: 64 blocks x 512 threads, deterministic placement ----
// totals + padded prefix derived from blockhist alone; block 0 publishes po[9]
// for GEMM2. Intra-block rank via LDS atomics only.
__global__ void scatter_kernel(const int* __restrict__ types,
                               const int* __restrict__ blockhist,
                               int* __restrict__ perm,
                               int* __restrict__ invperm,
                               float* __restrict__ outz,
                               int* __restrict__ po_out) {
    __shared__ int tots[8], base[8], fill[8];
    const int blk = blockIdx.x;            // 64
    const int tid = threadIdx.x;           // 512
    const int i = blk * 512 + tid;
    outz[i] = 0.f;
    int pre = 0;
    if (tid < 8) {
        int total = 0;
        for (int j = 0; j < 64; j++) {
            int v = blockhist[j * 8 + tid];
            if (j < blk) pre += v;
            total += v;
        }
        tots[tid] = total;
    }
    __syncthreads();
    if (tid < 8) {
        int off = 0, pob = 0;
        #pragma unroll
        for (int t2 = 0; t2 < 8; t2++) {
            if (t2 == tid) pob = off;
            off += ((tots[t2] + 127) >> 7) << 7;
        }
        base[tid] = pob + pre;
        fill[tid] = 0;
        if (blk == 0) {
            po_out[tid] = pob;
            if (tid == 0) po_out[8] = off;
        }
    }
    __syncthreads();
    const int t = types[i];
    const int r = atomicAdd(&fill[t], 1);  // LDS atomic: intra-block rank
    const int p = base[t] + r;
    perm[p] = i;
    invperm[i] = p;
}

// ---------- GEMM1 (fp8): 256x256 tile, BK=128, 8 waves, phased schedule --------
// (R1: measured neutral vs the 128^2 4-block/CU variant; kept -- passed with
// bit-identical absmax. Not iterating further on this unmeasurable dispatch.)
__global__ __launch_bounds__(512, 2)
void gemm1_fp8_8ph(const unsigned char* __restrict__ A,
                   const unsigned char* __restrict__ B,
                   unsigned char* __restrict__ C8,
                   const int* __restrict__ invperm) {
    __shared__ unsigned char As[2][256 * 128];
    __shared__ unsigned char Bs[2][256 * 128];
    __shared__ int ptile[256];

    const int tid  = threadIdx.x;
    const int wave = tid >> 6;
    const int lane = tid & 63;
    const int quad = lane >> 4;
    const int tl   = lane & 15;

    const int lin  = blockIdx.x;                 // 0..511
    const int sid  = (lin & 7) * 64 + (lin >> 3); // bijective XCD swizzle
    const int m0   = (sid >> 2) * 256;           // token tile
    const int n0   = (sid & 3) * 256;            // ff tile

    const int wm = (wave & 1) * 128;             // wave: 128 rows x 64 cols
    const int wn = (wave >> 1) * 64;

    if (tid < 256) ptile[tid] = invperm[m0 + tid];

    f32x4 acc[8][4];
    #pragma unroll
    for (int i = 0; i < 8; i++)
        #pragma unroll
        for (int j = 0; j < 4; j++)
            acc[i][j] = (f32x4){0.f, 0.f, 0.f, 0.f};

    // prologue: stage K-tile 0 into slot 0 (8 chunks/thread: 4 A + 4 B)
    #pragma unroll
    for (int ci = 0; ci < 8; ++ci) {
        const int c = ci * 512 + tid;
        if (ci < 4) {
            const int row = c >> 3, j = c & 7;
            async16(A + (size_t)(m0 + row) * 512 + j * 16, &As[0][c * 16]);
        } else {
            const int c2 = c - 2048;
            const int row = c2 >> 3, j = c2 & 7;
            async16(B + (size_t)(n0 + row) * 512 + j * 16, &Bs[0][c2 * 16]);
        }
    }
    asm volatile("s_waitcnt vmcnt(0)" ::: "memory");
    __builtin_amdgcn_s_barrier();
    asm volatile("" ::: "memory");

    for (int t = 0; t < 4; ++t) {                 // K = 512, BK = 128
        const unsigned char* Asl = As[t & 1];
        const unsigned char* Bsl = Bs[t & 1];
        unsigned char* Asn = As[(t + 1) & 1];
        unsigned char* Bsn = Bs[(t + 1) & 1];
        const int k0n = (t + 1) * 128;
        const bool st = (t < 3);
        #pragma unroll
        for (int ph = 0; ph < 8; ++ph) {          // ph = ks*2 + mh
            const int ks = ph >> 1, mh = ph & 1;
            const int o = (ks * 32 + quad * 8 + tl * 8) & 127;  // rotated frag offset
            long af[4], bfr[4];
            #pragma unroll
            for (int mt = 0; mt < 4; ++mt)
                af[mt] = *(const long*)(Asl + (wm + mh * 64 + mt * 16 + tl) * 128 + o);
            #pragma unroll
            for (int nt = 0; nt < 4; ++nt)
                bfr[nt] = *(const long*)(Bsl + (wn + nt * 16 + tl) * 128 + o);
            if (st && ph < 4) {
                // prefetch K-tile t+1 into the OTHER slot: 2 chunks/phase
                #pragma unroll
                for (int u = 0; u < 2; ++u) {
                    const int cidx = ph * 2 + u;      // 0..7 (compile-time)
                    const int c = cidx * 512 + tid;
                    if (cidx < 4) {
                        const int row = c >> 3, j = c & 7;
                        async16(A + (size_t)(m0 + row) * 512 + k0n + j * 16, Asn + c * 16);
                    } else {
                        const int c2 = c - 2048;
                        const int row = c2 >> 3, j = c2 & 7;
                        async16(B + (size_t)(n0 + row) * 512 + k0n + j * 16, Bsn + c2 * 16);
                    }
                }
            }
            __builtin_amdgcn_s_barrier();
            asm volatile("" ::: "memory");
            __builtin_amdgcn_s_setprio(1);
            #pragma unroll
            for (int mt = 0; mt < 4; ++mt)
                #pragma unroll
                for (int nt = 0; nt < 4; ++nt)
                    acc[mh * 4 + mt][nt] = __builtin_amdgcn_mfma_f32_16x16x32_fp8_fp8(
                        bfr[nt], af[mt], acc[mh * 4 + mt][nt], 0, 0, 0);  // swapped: D[n][tok]
            __builtin_amdgcn_s_setprio(0);
            if (ph == 7) asm volatile("s_waitcnt vmcnt(0)" ::: "memory");
            __builtin_amdgcn_s_barrier();
            asm volatile("" ::: "memory");
        }
    }

    // epilogue: lane holds 4 consecutive n (regs) for token tl; scatter via invperm
    #pragma unroll
    for (int mh = 0; mh < 2; ++mh)
        #pragma unroll
        for (int mt = 0; mt < 4; ++mt) {
            const int p = ptile[wm + mh * 64 + mt * 16 + tl];   // bucket position
            const size_t rowbase = (size_t)p * DFF;
            const int prot = (p & 15) << 3;
            #pragma unroll
            for (int nt = 0; nt < 4; ++nt) {
                const int off = wn + nt * 16 + quad * 4;        // 0..255 in n-tile
                unsigned int pk = pk4_fp8(fmaxf(acc[mh * 4 + mt][nt][0], 0.f) * 0.125f,
                                          fmaxf(acc[mh * 4 + mt][nt][1], 0.f) * 0.125f,
                                          fmaxf(acc[mh * 4 + mt][nt][2], 0.f) * 0.125f,
                                          fmaxf(acc[mh * 4 + mt][nt][3], 0.f) * 0.125f);
                const int phys = (off & ~127) + (((off & 127) + prot) & 127);
                *(unsigned int*)(C8 + rowbase + n0 + phys) = pk;
            }
        }
}

// ---------- fp8 GEMM2 (routed): 128x128 tile, BK=128, 4 waves, 16x16x32 fp8 ----
// R2 changes vs proven r9 structure (K-loop untouched):
//  - 1D grid + XCD-band swizzle: xcd = bid&7 owns a contiguous band of 33
//    m-tiles x all 4 n-tiles -> the 131KB A-panel is fetched once per XCD-L2
//    instead of 4x across XCDs (T1; kills the ~15MB over-fetch).
//  - batched epilogue: all 16 xres loads issued before any compute/store
//    (breaks the 16x serial ~900cy dependent chains at block end). Same ops,
//    same order per element -> bit-identical.
// MODE 1 (GEMM2): A=Xff8 bucket-order (contiguous); B per bucket via po[];
//                 epilogue via perm: Xb[tok] = bf16(Xb[tok]+relu(acc)/512)
template <int MODE>
__global__ __launch_bounds__(256, 4)
void gemm_fp8_kernel(const unsigned char* __restrict__ A,
                     const unsigned char* __restrict__ B,
                     void* __restrict__ Cout,
                     const unsigned short* __restrict__ xres,
                     const int* __restrict__ pmap,   // MODE0: invperm, MODE1: perm
                     const int* __restrict__ po,     // MODE1 only: padded offsets[9]
                     int K, int ldA) {
    __shared__ unsigned char As[128 * 128];
    __shared__ unsigned char Bs[128 * 128];
    __shared__ int ptile[128];

    const int tid  = threadIdx.x;
    const int wave = tid >> 6;
    const int lane = tid & 63;
    const int quad = lane >> 4;
    const int tl   = lane & 15;
    int m0, n0;
    if constexpr (MODE == 1) {
        // 1056 blocks; XCD-band swizzle (1056 % 8 == 0, bijective)
        const int sid = (blockIdx.x & 7) * 132 + (blockIdx.x >> 3);
        m0 = (sid >> 2) * 128;
        n0 = (sid & 3) * 128;
    } else {
        m0 = blockIdx.y * 128;
        n0 = blockIdx.x * 128;
    }
    const int wm = (wave & 1) * 64;
    const int wn = (wave >> 1) * 64;

    const unsigned char* Bp = B;
    if constexpr (MODE == 1) {
        if (m0 >= po[8]) return;                  // fully-padded tail block
        int bsel = 0;
        #pragma unroll
        for (int i = 1; i < 8; i++) bsel += (m0 >= po[i]) ? 1 : 0;
        Bp = B + (size_t)bsel * (DIN * DFF);
    }
    if (tid < 128) ptile[tid] = pmap[m0 + tid];

    f32x4 acc[4][4];
    #pragma unroll
    for (int i = 0; i < 4; i++)
        #pragma unroll
        for (int j = 0; j < 4; j++)
            acc[i][j] = (f32x4){0.f, 0.f, 0.f, 0.f};

    for (int k0 = 0; k0 < K; k0 += 128) {
        __syncthreads();
        // A tile [128][128]: 1024 x 16B chunks, 4/thread, LINEAR copy
        #pragma unroll
        for (int i = 0; i < 4; i++) {
            const int c   = (i * 4 + wave) * 64 + lane;
            const int row = c >> 3;
            const int j   = c & 7;
            async16(A + (size_t)(m0 + row) * ldA + k0 + j * 16, (char*)As + (size_t)c * 16);
        }
        // B tile [128][128], linear
        #pragma unroll
        for (int i = 0; i < 4; i++) {
            const int c   = (i * 4 + wave) * 64 + lane;
            const int row = c >> 3;
            const int j   = c & 7;
            async16(Bp + (size_t)(n0 + row) * K + k0 + j * 16, (char*)Bs + (size_t)c * 16);
        }
        __syncthreads();

        #pragma unroll
        for (int ks = 0; ks < 4; ks++) {
            long af[4], bfr[4];
            const int o = (ks * 32 + quad * 8 + tl * 8) & 127;  // rotated frag offset
            #pragma unroll
            for (int t = 0; t < 4; t++)
                af[t] = *(const long*)(As + (wm + t * 16 + tl) * 128 + o);
            #pragma unroll
            for (int t = 0; t < 4; t++)
                bfr[t] = *(const long*)(Bs + (wn + t * 16 + tl) * 128 + o);
            #pragma unroll
            for (int mt = 0; mt < 4; mt++)
                #pragma unroll
                for (int nt = 0; nt < 4; nt++)
                    acc[mt][nt] = __builtin_amdgcn_mfma_f32_16x16x32_fp8_fp8(
                        bfr[nt], af[mt], acc[mt][nt], 0, 0, 0);  // swapped: D[n][tok]
        }
    }

    // epilogue: lane holds 4 consecutive n (regs) for token tl
    if constexpr (MODE == 0) {
        unsigned char* C8 = (unsigned char*)Cout;
        #pragma unroll
        for (int mt = 0; mt < 4; mt++) {
            const int p = ptile[wm + mt * 16 + tl];            // bucket position
            const size_t rowbase = (size_t)p * DFF;
            const int prot = (p & 15) << 3;
            #pragma unroll
            for (int nt = 0; nt < 4; nt++) {
                const int off = wn + nt * 16 + quad * 4;       // in-window offset
                unsigned int pk = pk4_fp8(fmaxf(acc[mt][nt][0], 0.f) * 0.125f,
                                          fmaxf(acc[mt][nt][1], 0.f) * 0.125f,
                                          fmaxf(acc[mt][nt][2], 0.f) * 0.125f,
                                          fmaxf(acc[mt][nt][3], 0.f) * 0.125f);
                const int phys = (off & ~127) + (((off & 127) + prot) & 127);
                *(unsigned int*)(C8 + rowbase + n0 + phys) = pk;
            }
        }
    } else {
        unsigned short* Cb = (unsigned short*)Cout;
        int toks[4];
        #pragma unroll
        for (int mt = 0; mt < 4; mt++) toks[mt] = ptile[wm + mt * 16 + tl];
        // batch ALL residual loads first (breaks serial dependent chains)
        ushort4 rv[4][4];
        #pragma unroll
        for (int mt = 0; mt < 4; mt++) {
            if (toks[mt] < 0) continue;
            const size_t rowbase = (size_t)toks[mt] * DIN;
            #pragma unroll
            for (int nt = 0; nt < 4; nt++)
                rv[mt][nt] = *(const ushort4*)(xres + rowbase + n0 + wn + nt * 16 + quad * 4);
        }
        #pragma unroll
        for (int mt = 0; mt < 4; mt++) {
            if (toks[mt] < 0) continue;
            const size_t rowbase = (size_t)toks[mt] * DIN;
            #pragma unroll
            for (int nt = 0; nt < 4; nt++) {
                const int ncol = n0 + wn + nt * 16 + quad * 4;
                ushort4 o;
                o.x = f2bf(bf2f(rv[mt][nt].x) + fmaxf(acc[mt][nt][0], 0.f) * 0.001953125f);
                o.y = f2bf(bf2f(rv[mt][nt].y) + fmaxf(acc[mt][nt][1], 0.f) * 0.001953125f);
                o.z = f2bf(bf2f(rv[mt][nt].z) + fmaxf(acc[mt][nt][2], 0.f) * 0.001953125f);
                o.w = f2bf(bf2f(rv[mt][nt].w) + fmaxf(acc[mt][nt][3], 0.f) * 0.001953125f);
                *(ushort4*)(Cb + rowbase + ncol) = o;
            }
        }
    }
}

// ------- bf16 GEMM3 + head (kept full precision): 128x256 tile, 512 thr --------
// out[tok] += relu(Xb @ W_c1) . w2   (atomicAdd partials per n-block)
// R2: 1D grid + XCD-band swizzle (512 % 8 == 0): each XCD owns 32 consecutive
// m-tiles x both n-tiles -> A-tile L2 reuse.
__global__ __launch_bounds__(512, 4)
void gemm3_kernel(const unsigned short* __restrict__ A,
                  const unsigned short* __restrict__ B,
                  const float* __restrict__ w2,
                  float* __restrict__ outp,
                  int K, int ldA) {
    __shared__ unsigned short As[128 * 64];
    __shared__ unsigned short Bs[256 * 64];

    const int tid  = threadIdx.x;
    const int wave = tid >> 6;
    const int lane = tid & 63;
    const int quad = lane >> 4;
    const int tl   = lane & 15;
    const int sid = (blockIdx.x & 7) * 64 + (blockIdx.x >> 3);
    const int m0 = (sid >> 1) * 128;
    const int n0 = (sid & 1) * 256;
    const int wm = (wave & 1) * 64;
    const int wn = (wave >> 1) * 64;

    f32x4 acc[4][4];
    #pragma unroll
    for (int i = 0; i < 4; i++)
        #pragma unroll
        for (int j = 0; j < 4; j++)
            acc[i][j] = (f32x4){0.f, 0.f, 0.f, 0.f};

    for (int k0 = 0; k0 < K; k0 += 64) {
        __syncthreads();
        #pragma unroll
        for (int i = 0; i < 2; i++) {
            const int c   = (i * 8 + wave) * 64 + lane;
            const int row = c >> 3;
            const int gj  = (c & 7) ^ (row & 7);
            async16(A + (size_t)(m0 + row) * ldA + k0 + gj * 8, (char*)As + (size_t)c * 16);
        }
        #pragma unroll
        for (int i = 0; i < 4; i++) {
            const int c   = (i * 8 + wave) * 64 + lane;
            const int row = c >> 3;
            const int gj  = (c & 7) ^ (row & 7);
            async16(B + (size_t)(n0 + row) * K + k0 + gj * 8, (char*)Bs + (size_t)c * 16);
        }
        __syncthreads();

        #pragma unroll
        for (int ks = 0; ks < 2; ks++) {
            bf16x8 af[4], bfr[4];
            const int jc = ks * 4 + quad;
            #pragma unroll
            for (int t = 0; t < 4; t++) {
                const int r = wm + t * 16 + tl;
                af[t] = *(const bf16x8*)(As + (r * 8 + (jc ^ (r & 7))) * 8);
            }
            #pragma unroll
            for (int t = 0; t < 4; t++) {
                const int r = wn + t * 16 + tl;
                bfr[t] = *(const bf16x8*)(Bs + (r * 8 + (jc ^ (r & 7))) * 8);
            }
            #pragma unroll
            for (int mt = 0; mt < 4; mt++)
                #pragma unroll
                for (int nt = 0; nt < 4; nt++)
                    acc[mt][nt] = __builtin_amdgcn_mfma_f32_16x16x32_bf16(
                        bfr[nt], af[mt], acc[mt][nt], 0, 0, 0);
        }
    }

    float4 w2v[4];
    #pragma unroll
    for (int nt = 0; nt < 4; nt++)
        w2v[nt] = *(const float4*)(w2 + n0 + wn + nt * 16 + quad * 4);
    #pragma unroll
    for (int mt = 0; mt < 4; mt++) {
        float s = 0.f;
        #pragma unroll
        for (int nt = 0; nt < 4; nt++) {
            s += fmaxf(acc[mt][nt][0], 0.f) * w2v[nt].x;
            s += fmaxf(acc[mt][nt][1], 0.f) * w2v[nt].y;
            s += fmaxf(acc[mt][nt][2], 0.f) * w2v[nt].z;
            s += fmaxf(acc[mt][nt][3], 0.f) * w2v[nt].w;
        }
        s += __shfl_down(s, 32);
        s += __shfl_down(s, 16);
        if (lane < 16) atomicAdd(&outp[m0 + wm + mt * 16 + lane], s);
    }
}

extern "C" void kernel_launch(void* const* d_in, const int* in_sizes, int n_in,
                              void* d_out, int out_size, void* d_ws, size_t ws_size,
                              hipStream_t stream) {
    const float* x      = (const float*)d_in[0];
    const int*   types  = (const int*)d_in[1];
    const float* W_pre  = (const float*)d_in[2];
    const float* W_types= (const float*)d_in[3];
    const float* W_c1   = (const float*)d_in[4];
    const float* W_c2   = (const float*)d_in[5];
    float* out = (float*)d_out;

    // workspace layout (~91 MB):
    char* ws = (char*)d_ws;
    unsigned short* Xb  = (unsigned short*)(ws);                    // bf16 [32768][512], becomes X_res
    unsigned char*  Xff8= (unsigned char*)(ws + 33554432ull);       // fp8 [MPAD][1024] = 8*x_, bucket order, k-rotated
    unsigned char*  Xb8 = (unsigned char*)(ws + 68157440ull);       // fp8 [32768][512] = x, k-rotated
    unsigned char*  Wp8 = (unsigned char*)(ws + 84934656ull);       // fp8 [1024][512] (x64, rotated)
    unsigned char*  Wt8 = (unsigned char*)(ws + 85458944ull);       // fp8 [8][512][1024] (x64, rotated)
    unsigned short* WcT = (unsigned short*)(ws + 89653248ull);      // bf16 [512][512]
    int* perm           = (int*)(ws + 90177536ull);                  // MPAD ints
    int* invperm        = (int*)(ws + 90312704ull);                  // N_TOK ints
    int* po             = (int*)(ws + 90443776ull);                  // 9 ints (padded offsets)
    int* blockhist      = po + 16;                                   // 64*8 ints

    // 1) merged prep: tokens [0,16384), weights [16384,26624), perm-pad [26624,26756)
    prep_kernel<<<26756, 256, 0, stream>>>(x, Xb, Xb8, types, blockhist,
                                           W_pre, W_types, W_c1, Wp8, Wt8, WcT, perm);
    // 2) deterministic scatter + po publish + out zero
    scatter_kernel<<<64, 512, 0, stream>>>(types, blockhist, perm, invperm, out, po);
    // 3) GEMM1 (fp8, 8-phase 256^2): Xff8[invperm[tok]] = fp8(8 * relu(x @ W_pre))
    gemm1_fp8_8ph<<<512, 512, 0, stream>>>(Xb8, Wp8, Xff8, invperm);
    // 4) GEMM2 (fp8, routed, XCD-banded 1D grid): Xb = bf16(Xb + relu(Xff8 @ Wt8[b]) / 512)
    gemm_fp8_kernel<1><<<1056, 256, 0, stream>>>(
        Xff8, Wt8, Xb, Xb, perm, po, 1024, 1024);
    // 5) GEMM3 + head (bf16, XCD-banded 1D grid): out = relu(Xb @ W_c1) @ W_c2
    gemm3_kernel<<<512, 512, 0, stream>>>(
        Xb, WcT, W_c2, out, 512, 512);
}